// Round 11
// baseline (384.949 us; speedup 1.0000x reference)
//
#include <hip/hip_runtime.h>
#include <hip/hip_bf16.h>
#include <math.h>

using ushort8 = __attribute__((ext_vector_type(8))) unsigned short;
using short8  = __attribute__((ext_vector_type(8))) short;
using f32x4   = __attribute__((ext_vector_type(4))) float;
using f32x2   = __attribute__((ext_vector_type(2))) float;

__device__ __forceinline__ float bf2f(unsigned short u) {
    union { unsigned int i; float f; } c; c.i = ((unsigned int)u) << 16; return c.f;
}
__device__ __forceinline__ unsigned short f2bf(float f) {
    __hip_bfloat16 h = __float2bfloat16(f);
    return *reinterpret_cast<unsigned short*>(&h);
}
__device__ __forceinline__ unsigned char f2fp8(float f) {
    int p = __builtin_amdgcn_cvt_pk_fp8_f32(f, 0.f, 0, false);
    return (unsigned char)(p & 0xff);
}
__device__ __forceinline__ float silu_f(float x) { return x / (1.f + __expf(-x)); }
__device__ __forceinline__ float gelu_f(float x) {
    float x3 = x * x * x;
    return 0.5f * x * (1.f + tanhf(0.7978845608028654f * (x + 0.044715f * x3)));
}

// QKV packed row: 1792 bytes = q[512] fp8 | kv[1024] fp8 | skip[128] bf16
constexpr int QKV_STRIDE_B = 1792;

// ---------------------------------------------------------------------------
// Async global->LDS tile stage with pre-swizzled global source (m173 pattern).
// Per-wave issue count: (nrows/8)/4 chunks for A + 4 for B (128 rows).
// ---------------------------------------------------------------------------
__device__ __forceinline__ void stage_tile_async(
    const unsigned short* __restrict__ gbase,   // points at (row 0, k0)
    int K, unsigned short (*lds)[64], int nrows, int wid, int lane)
{
    int nch = nrows >> 3;
#pragma unroll
    for (int c = wid; c < nch; c += 4) {
        int n0 = c * 8;
        int n = n0 + (lane >> 3);
        int b = (lane & 7) ^ (n & 7);
        const unsigned short* src = gbase + (size_t)n * K + b * 8;
        __builtin_amdgcn_global_load_lds(
            (const __attribute__((address_space(1))) unsigned int*)src,
            (__attribute__((address_space(3))) unsigned int*)&lds[n0][0],
            16, 0, 0);
    }
}

// ---------------------------------------------------------------------------
// bf16 MFMA GEMM: C = epi(A @ Wt^T + bias)   [BK=64 loop, A bf16, async stage]
// Grid: dim3(M/128, rowBlocks); bijective chunked XCD swizzle.
// EPI: 0=none 1=gelu 2=res+val 3=res+gate*val 4=qkv pack 5=res+val + fused
//      LN+modulate -> out2 bf16   6=fp8 out
// PIPE=1 (WM=2 only): double-buffered LDS, counted vmcnt(6), raw barriers —
//      for latency-exposed small grids (~1 block/CU).
// ---------------------------------------------------------------------------
template<int WM, int EPI, int OUTBF, int PIPE = 0>
__global__ __launch_bounds__(256) void gemm_mfma(
    const void* __restrict__ Ain, const unsigned short* __restrict__ Wt,
    const float* __restrict__ bias, void* __restrict__ Cout,
    const float* __restrict__ res, const void* __restrict__ gatep,
    void* __restrict__ out2, int Nrows, int K, int M)
{
    constexpr int BM = 32 * WM;
    static_assert(PIPE == 0 || WM == 2, "PIPE path assumes WM==2 (vmcnt literal)");
    __shared__ unsigned short As[(PIPE ? 2 : 1) * BM][64];
    __shared__ unsigned short Bs[(PIPE ? 2 : 1) * 128][64];
    const int tid = threadIdx.x;
    const int gx = gridDim.x;
    const int T = gx * gridDim.y;
    const int hw = blockIdx.y * gx + blockIdx.x;
    const int q = T >> 3, r = T & 7, xc = hw & 7, j = hw >> 3;
    const int work = (xc < r ? xc * (q + 1) : r * (q + 1) + (xc - r) * q) + j;
    const int row0 = (work / gx) * BM;
    const int col0 = (work % gx) * 128;
    const int lane = tid & 63;
    const int wid  = tid >> 6;
    const int wr = (wid >> 1) * 16 * WM;
    const int wc = (wid & 1) * 64;
    const int lr = lane & 15;
    const int lk = lane >> 4;

    f32x4 acc[WM][4];
#pragma unroll
    for (int i = 0; i < WM; i++)
#pragma unroll
        for (int jj = 0; jj < 4; jj++) acc[i][jj] = (f32x4)0.f;

    if constexpr (PIPE == 1) {
        const int KI = K >> 6;
        // prologue: stage tile 0 into buffer 0
        stage_tile_async((const unsigned short*)Ain + (size_t)row0 * K, K, As, BM, wid, lane);
        stage_tile_async(Wt + (size_t)col0 * K, K, Bs, 128, wid, lane);
        for (int t = 0; t < KI; ++t) {
            unsigned short (*Asb)[64] = As + (t & 1) * BM;
            unsigned short (*Bsb)[64] = Bs + (t & 1) * 128;
            if (t + 1 < KI) {
                int k1 = (t + 1) * 64;
                stage_tile_async((const unsigned short*)Ain + (size_t)row0 * K + k1,
                                 K, As + ((t + 1) & 1) * BM, BM, wid, lane);
                stage_tile_async(Wt + (size_t)col0 * K + k1,
                                 K, Bs + ((t + 1) & 1) * 128, 128, wid, lane);
                // 6 newest (next tile) stay in flight; current tile's 6 are done
                asm volatile("s_waitcnt vmcnt(6)" ::: "memory");
            } else {
                asm volatile("s_waitcnt vmcnt(0)" ::: "memory");
            }
            __builtin_amdgcn_s_barrier();
            __builtin_amdgcn_sched_barrier(0);

            short8 afr[WM][2], bfr[4][2];
#pragma unroll
            for (int fr = 0; fr < WM; fr++)
#pragma unroll
                for (int s = 0; s < 2; s++) {
                    int m = wr + fr * 16 + lr;
                    int blk = (s * 4 + lk) ^ (m & 7);
                    afr[fr][s] = *(const short8*)&Asb[m][blk * 8];
                }
#pragma unroll
            for (int fc = 0; fc < 4; fc++)
#pragma unroll
                for (int s = 0; s < 2; s++) {
                    int n = wc + fc * 16 + lr;
                    int blk = (s * 4 + lk) ^ (n & 7);
                    bfr[fc][s] = *(const short8*)&Bsb[n][blk * 8];
                }
#pragma unroll
            for (int fr = 0; fr < WM; fr++)
#pragma unroll
                for (int fc = 0; fc < 4; fc++)
#pragma unroll
                    for (int s = 0; s < 2; s++)
                        acc[fr][fc] = __builtin_amdgcn_mfma_f32_16x16x32_bf16(
                            afr[fr][s], bfr[fc][s], acc[fr][fc], 0, 0, 0);
            __builtin_amdgcn_s_barrier();
            __builtin_amdgcn_sched_barrier(0);
        }
    } else {
        for (int k0 = 0; k0 < K; k0 += 64) {
            stage_tile_async((const unsigned short*)Ain + (size_t)row0 * K + k0,
                             K, As, BM, wid, lane);
            stage_tile_async(Wt + (size_t)col0 * K + k0, K, Bs, 128, wid, lane);
            __syncthreads();

            short8 afr[WM][2], bfr[4][2];
#pragma unroll
            for (int fr = 0; fr < WM; fr++)
#pragma unroll
                for (int s = 0; s < 2; s++) {
                    int m = wr + fr * 16 + lr;
                    int blk = (s * 4 + lk) ^ (m & 7);
                    afr[fr][s] = *(const short8*)&As[m][blk * 8];
                }
#pragma unroll
            for (int fc = 0; fc < 4; fc++)
#pragma unroll
                for (int s = 0; s < 2; s++) {
                    int n = wc + fc * 16 + lr;
                    int blk = (s * 4 + lk) ^ (n & 7);
                    bfr[fc][s] = *(const short8*)&Bs[n][blk * 8];
                }
#pragma unroll
            for (int fr = 0; fr < WM; fr++)
#pragma unroll
                for (int fc = 0; fc < 4; fc++)
#pragma unroll
                    for (int s = 0; s < 2; s++)
                        acc[fr][fc] = __builtin_amdgcn_mfma_f32_16x16x32_bf16(
                            afr[fr][s], bfr[fc][s], acc[fr][fc], 0, 0, 0);
            __syncthreads();
        }
    }

#pragma unroll
    for (int fr = 0; fr < WM; fr++) {
#pragma unroll
        for (int fc = 0; fc < 4; fc++) {
#pragma unroll
            for (int rr = 0; rr < 4; rr++) {
                int lrow = wr + fr * 16 + (lane >> 4) * 4 + rr;
                int row = row0 + lrow;
                if (row >= Nrows) continue;
                int col = col0 + wc + fc * 16 + (lane & 15);
                float val = acc[fr][fc][rr] + bias[col];
                if (EPI == 4) {
                    unsigned char* rowp = (unsigned char*)Cout + (size_t)row * QKV_STRIDE_B;
                    if (col < 1536) {
                        rowp[col] = f2fp8(val);            // q fp8 | kv fp8
                    } else {
                        *(unsigned short*)(rowp + 1536 + 2 * (col - 1536)) = f2bf(val);
                    }
                } else if (EPI == 5) {
                    size_t idx = (size_t)row * M + col;
                    float x2 = res[idx] + val;
                    ((float*)Cout)[idx] = x2;
                    (&Bs[0][0])[lrow * 128 + col - col0] = f2bf(x2);
                } else if (EPI == 6) {
                    ((unsigned char*)Cout)[(size_t)row * M + col] = f2fp8(val);
                } else {
                    size_t idx = (size_t)row * M + col;
                    if (EPI == 1) val = gelu_f(val);
                    else if (EPI == 2) val = res[idx] + val;
                    else if (EPI == 3) val = res[idx] +
                        bf2f(((const unsigned short*)gatep)[(size_t)row * 768 + col]) * val;
                    if (OUTBF) ((unsigned short*)Cout)[idx] = f2bf(val);
                    else       ((float*)Cout)[idx] = val;
                }
            }
        }
    }

    if constexpr (EPI == 5) {
        __syncthreads();
        const unsigned short* x2b = &Bs[0][0];
        const unsigned short* mod = (const unsigned short*)gatep;
        for (int rr = wid; rr < BM; rr += 4) {
            int row = row0 + rr;
            if (row >= Nrows) continue;
            ushort2 xv = *(const ushort2*)&x2b[rr * 128 + lane * 2];
            float v0 = bf2f(xv.x), v1 = bf2f(xv.y);
            float s = v0 + v1, ss = v0 * v0 + v1 * v1;
#pragma unroll
            for (int mm = 1; mm < 64; mm <<= 1) {
                s += __shfl_xor(s, mm); ss += __shfl_xor(ss, mm);
            }
            float mu = s * (1.f / 128.f);
            float rs = rsqrtf(ss * (1.f / 128.f) - mu * mu + 1e-6f);
            const unsigned short* mp = mod + (size_t)row * 768;
            ushort2 sh = *(const ushort2*)(mp + 384 + lane * 2);
            ushort2 sc = *(const ushort2*)(mp + 512 + lane * 2);
            ushort2 o;
            o.x = f2bf((v0 - mu) * rs * (1.f + bf2f(sc.x)) + bf2f(sh.x));
            o.y = f2bf((v1 - mu) * rs * (1.f + bf2f(sc.y)) + bf2f(sh.y));
            *(ushort2*)((unsigned short*)out2 + (size_t)row * 128 + lane * 2) = o;
        }
    }
}

// ---------------------------------------------------------------------------
// ALL weight prep + silu(t)->bf16 in ONE kernel.
// ---------------------------------------------------------------------------
__global__ __launch_bounds__(256) void prep_all(
    const float* __restrict__ qW, const float* __restrict__ qB,
    const float* __restrict__ kW, const float* __restrict__ kB,
    const float* __restrict__ vW, const float* __restrict__ vB,
    const float* __restrict__ sW, const float* __restrict__ sB,
    const float* __restrict__ f1W, const float* __restrict__ f2W,
    const float* __restrict__ adW,
    unsigned short* __restrict__ Wsa_t, float* __restrict__ bsa,
    unsigned short* __restrict__ fc1_t, unsigned short* __restrict__ fc2_t,
    unsigned short* __restrict__ ada_t,
    const float* __restrict__ Wq, const float* __restrict__ bq,
    const float* __restrict__ Wk, const float* __restrict__ Wv,
    const float* __restrict__ bv, const float* __restrict__ Wo,
    const float* __restrict__ bo,
    unsigned short* __restrict__ Mcat_t, float* __restrict__ biasM,
    unsigned short* __restrict__ Pcat_t, float* __restrict__ co,
    const float* __restrict__ t_in, unsigned short* __restrict__ Tbuf, int n8)
{
    int g = blockIdx.x * 256 + threadIdx.x;
    if (g < 65536) {                       // sa_q
        int m = g >> 7, kk = g & 127;
        Wsa_t[m * 128 + kk] = f2bf(qW[(size_t)kk * 512 + m]);
        if (kk == 0) bsa[m] = qB[m];
    } else if (g < 131072) {               // sa_k (lane-16B layout)
        int l = g - 65536; int m = l >> 7, kk = l & 127;
        int h = m >> 7, dl = m & 127;
        int p = 512 + h * 256 + ((dl >> 3) << 4) + (dl & 7);
        Wsa_t[p * 128 + kk] = f2bf(kW[(size_t)kk * 512 + m]);
        if (kk == 0) bsa[p] = kB[m];
    } else if (g < 196608) {               // sa_v (lane-16B layout)
        int l = g - 131072; int m = l >> 7, kk = l & 127;
        int h = m >> 7, dl = m & 127;
        int p = 512 + h * 256 + ((dl >> 3) << 4) + 8 + (dl & 7);
        Wsa_t[p * 128 + kk] = f2bf(vW[(size_t)kk * 512 + m]);
        if (kk == 0) bsa[p] = vB[m];
    } else if (g < 212992) {               // sa_skip
        int l = g - 196608; int m = l >> 7, kk = l & 127;
        Wsa_t[(1536 + m) * 128 + kk] = f2bf(sW[(size_t)kk * 128 + m]);
        if (kk == 0) bsa[1536 + m] = sB[m];
    } else if (g < 278528) {               // fc1
        int l = g - 212992; int m = l >> 7, kk = l & 127;
        fc1_t[m * 128 + kk] = f2bf(f1W[(size_t)kk * 512 + m]);
    } else if (g < 344064) {               // fc2
        int l = g - 278528; int m = l >> 9, kk = l & 511;
        fc2_t[m * 512 + kk] = f2bf(f2W[(size_t)kk * 128 + m]);
    } else if (g < 442368) {               // ada
        int l = g - 344064; int m = l >> 7, kk = l & 127;
        ada_t[m * 128 + kk] = f2bf(adW[(size_t)kk * 768 + m]);
    } else if (g < 507904) {               // folded cross-attn weights
        int g2 = g - 442368;               // 0..65535
        {
            int i0 = g2 >> 9, col = g2 & 511, h = col >> 7, i = col & 127;
            float s = 0.f;
#pragma unroll 8
            for (int jj = 0; jj < 32; jj++)
                s += Wq[i0 * 128 + h * 32 + jj] * Wk[i * 128 + h * 32 + jj];
            Mcat_t[col * 128 + i0] = f2bf(s);
        }
        {
            int rowp = g2 >> 7, jc = g2 & 127, h = rowp >> 7, i = rowp & 127;
            float s = 0.f;
#pragma unroll 8
            for (int d = 0; d < 32; d++)
                s += Wv[i * 128 + h * 32 + d] * Wo[(h * 32 + d) * 128 + jc];
            Pcat_t[jc * 512 + rowp] = f2bf(s);
        }
        if (g2 < 512) {
            int h = g2 >> 7, i = g2 & 127;
            float s = 0.f;
            for (int jj = 0; jj < 32; jj++)
                s += bq[h * 32 + jj] * Wk[i * 128 + h * 32 + jj];
            biasM[g2] = s;
        }
        if (g2 < 128) {
            float s = bo[g2];
            for (int m = 0; m < 128; m++) s += bv[m] * Wo[m * 128 + g2];
            co[g2] = s;
        }
    } else {                               // silu(t) -> bf16, 8 elems/thread
        int i = g - 507904;
        if (i < n8) {
            const float* p = t_in + (size_t)i * 8;
            float4 a = *(const float4*)p, b = *(const float4*)(p + 4);
            float v[8] = {a.x, a.y, a.z, a.w, b.x, b.y, b.z, b.w};
            ushort8 h;
#pragma unroll
            for (int jj = 0; jj < 8; jj++) h[jj] = f2bf(silu_f(v[jj]));
            *(ushort8*)(Tbuf + (size_t)i * 8) = h;
        }
    }
}

// ---------------------------------------------------------------------------
// LN + modulate, one WAVE per node (xm for the QKV projection).
// ---------------------------------------------------------------------------
__global__ __launch_bounds__(256) void ln_mod_kernel(
    const float* __restrict__ x, const unsigned short* __restrict__ mod,
    int shift_off, int scale_off, unsigned short* __restrict__ outb, int N)
{
    int node = blockIdx.x * 4 + (threadIdx.x >> 6);
    if (node >= N) return;
    int lane = threadIdx.x & 63;
    f32x2 v = *(const f32x2*)(x + (size_t)node * 128 + lane * 2);
    float s = v[0] + v[1], ss = v[0] * v[0] + v[1] * v[1];
#pragma unroll
    for (int m = 1; m < 64; m <<= 1) { s += __shfl_xor(s, m); ss += __shfl_xor(ss, m); }
    float mu = s * (1.f / 128.f);
    float rs = rsqrtf(ss * (1.f / 128.f) - mu * mu + 1e-6f);
    const unsigned short* mp = mod + (size_t)node * 768;
    ushort2 sh = *(const ushort2*)(mp + shift_off + lane * 2);
    ushort2 sc = *(const ushort2*)(mp + scale_off + lane * 2);
    ushort2 o;
    o.x = f2bf((v[0] - mu) * rs * (1.f + bf2f(sc.x)) + bf2f(sh.x));
    o.y = f2bf((v[1] - mu) * rs * (1.f + bf2f(sc.y)) + bf2f(sh.y));
    *(ushort2*)(outb + (size_t)node * 128 + lane * 2) = o;
}

// ---------------------------------------------------------------------------
// CSR build
// ---------------------------------------------------------------------------
__global__ void count_edges(const int* __restrict__ dst, int* __restrict__ count, int E) {
    int e = blockIdx.x * blockDim.x + threadIdx.x;
    if (e < E) atomicAdd(&count[dst[e]], 1);
}

// single-launch scan: 1 block, 1024 threads, thread-coarsened two-pass
__global__ __launch_bounds__(1024) void scan_all(
    const int* __restrict__ cnt, int* __restrict__ base,
    int* __restrict__ cursor, int n)
{
    int tid = threadIdx.x;
    int per = (n + 1023) >> 10;
    int start = tid * per;
    int s = 0;
    for (int i = 0; i < per; ++i) {
        int idx = start + i;
        s += (idx < n) ? cnt[idx] : 0;
    }
    int lane = tid & 63, w = tid >> 6;
    int inc = s;
#pragma unroll
    for (int off = 1; off < 64; off <<= 1) {
        int t = __shfl_up(inc, off);
        if (lane >= off) inc += t;
    }
    __shared__ int wsum[16];
    if (lane == 63) wsum[w] = inc;
    __syncthreads();
    if (w == 0 && lane < 16) {
        int v = wsum[lane];
#pragma unroll
        for (int off = 1; off < 16; off <<= 1) {
            int t = __shfl_up(v, off);
            if (lane >= off) v += t;
        }
        wsum[lane] = v;
    }
    __syncthreads();
    int running = inc - s + (w > 0 ? wsum[w - 1] : 0);
    for (int i = 0; i < per; ++i) {
        int idx = start + i;
        if (idx < n) {
            int v = cnt[idx];
            running += v;
            base[idx + 1] = running;
            cursor[idx] = running - v;
        }
    }
    if (tid == 0) base[0] = 0;
}

__global__ void scatter_edges(const int* __restrict__ src, const int* __restrict__ dst,
                              int* __restrict__ cursor, int* __restrict__ csr_src, int E) {
    int e = blockIdx.x * blockDim.x + threadIdx.x;
    if (e < E) {
        int pos = atomicAdd(&cursor[dst[e]], 1);
        csr_src[pos] = src[e];
    }
}

// ---------------------------------------------------------------------------
// Graph self-attention + residual + fused norm3 LN. ONE WAVE per node.
// q fp8 (bytes l*8..+7), kv fp8 (512 + l*16), skip bf16 (1536 + 2*dim).
// ---------------------------------------------------------------------------
__global__ __launch_bounds__(64) void sa_node_kernel(
    const unsigned char* __restrict__ qkv,
    const int* __restrict__ base, const int* __restrict__ csr_src,
    const float* __restrict__ x, const unsigned short* __restrict__ mod,
    const float* __restrict__ n3g, const float* __restrict__ n3b,
    float* __restrict__ x1, unsigned short* __restrict__ qn)
{
    int node = blockIdx.x, l = threadIdx.x;
    const unsigned char* nrow = qkv + (size_t)node * QKV_STRIDE_B;
    uint2 qb = *(const uint2*)(nrow + l * 8);
    const float scl = 0.08838834764831845f;          // 1/sqrt(128)
    float q[8];
    {
        f32x2 qA = __builtin_amdgcn_cvt_pk_f32_fp8(qb.x, false);
        f32x2 qB = __builtin_amdgcn_cvt_pk_f32_fp8(qb.x, true);
        f32x2 qC = __builtin_amdgcn_cvt_pk_f32_fp8(qb.y, false);
        f32x2 qD = __builtin_amdgcn_cvt_pk_f32_fp8(qb.y, true);
        q[0] = qA[0] * scl; q[1] = qA[1] * scl;
        q[2] = qB[0] * scl; q[3] = qB[1] * scl;
        q[4] = qC[0] * scl; q[5] = qC[1] * scl;
        q[6] = qD[0] * scl; q[7] = qD[1] * scl;
    }
    int beg = base[node], end = base[node + 1];
    float den = 0.f;
    float a[8];
#pragma unroll
    for (int jj = 0; jj < 8; jj++) a[jj] = 0.f;
    uint4 c0 = make_uint4(0, 0, 0, 0), c1 = c0;
    if (beg < end)
        c0 = *(const uint4*)(qkv + (size_t)csr_src[beg] * QKV_STRIDE_B + 512 + l * 16);
    if (beg + 1 < end)
        c1 = *(const uint4*)(qkv + (size_t)csr_src[beg + 1] * QKV_STRIDE_B + 512 + l * 16);
    for (int e = beg; e < end; e += 2) {
        uint4 m0 = c0, m1 = c1;
        if (e + 2 < end)
            c0 = *(const uint4*)(qkv + (size_t)csr_src[e + 2] * QKV_STRIDE_B + 512 + l * 16);
        if (e + 3 < end)
            c1 = *(const uint4*)(qkv + (size_t)csr_src[e + 3] * QKV_STRIDE_B + 512 + l * 16);
        f32x2 kA, kB, kC, kD;
        kA = __builtin_amdgcn_cvt_pk_f32_fp8(m0.x, false);
        kB = __builtin_amdgcn_cvt_pk_f32_fp8(m0.x, true);
        kC = __builtin_amdgcn_cvt_pk_f32_fp8(m0.y, false);
        kD = __builtin_amdgcn_cvt_pk_f32_fp8(m0.y, true);
        float p0 = q[0]*kA[0] + q[1]*kA[1] + q[2]*kB[0] + q[3]*kB[1]
                 + q[4]*kC[0] + q[5]*kC[1] + q[6]*kD[0] + q[7]*kD[1];
        kA = __builtin_amdgcn_cvt_pk_f32_fp8(m1.x, false);
        kB = __builtin_amdgcn_cvt_pk_f32_fp8(m1.x, true);
        kC = __builtin_amdgcn_cvt_pk_f32_fp8(m1.y, false);
        kD = __builtin_amdgcn_cvt_pk_f32_fp8(m1.y, true);
        float p1 = q[0]*kA[0] + q[1]*kA[1] + q[2]*kB[0] + q[3]*kB[1]
                 + q[4]*kC[0] + q[5]*kC[1] + q[6]*kD[0] + q[7]*kD[1];
#pragma unroll
        for (int mm = 1; mm < 16; mm <<= 1) {
            p0 += __shfl_xor(p0, mm);
            p1 += __shfl_xor(p1, mm);
        }
        float pe0 = __expf(fminf(p0, 80.f));
        float pe1 = (e + 1 < end) ? __expf(fminf(p1, 80.f)) : 0.f;
        den += pe0 + pe1;
        f32x2 vA, vB, vC, vD, wA, wB, wC, wD;
        vA = __builtin_amdgcn_cvt_pk_f32_fp8(m0.z, false);
        vB = __builtin_amdgcn_cvt_pk_f32_fp8(m0.z, true);
        vC = __builtin_amdgcn_cvt_pk_f32_fp8(m0.w, false);
        vD = __builtin_amdgcn_cvt_pk_f32_fp8(m0.w, true);
        wA = __builtin_amdgcn_cvt_pk_f32_fp8(m1.z, false);
        wB = __builtin_amdgcn_cvt_pk_f32_fp8(m1.z, true);
        wC = __builtin_amdgcn_cvt_pk_f32_fp8(m1.w, false);
        wD = __builtin_amdgcn_cvt_pk_f32_fp8(m1.w, true);
        a[0] += pe0 * vA[0] + pe1 * wA[0];
        a[1] += pe0 * vA[1] + pe1 * wA[1];
        a[2] += pe0 * vB[0] + pe1 * wB[0];
        a[3] += pe0 * vB[1] + pe1 * wB[1];
        a[4] += pe0 * vC[0] + pe1 * wC[0];
        a[5] += pe0 * vC[1] + pe1 * wC[1];
        a[6] += pe0 * vD[0] + pe1 * wD[0];
        a[7] += pe0 * vD[1] + pe1 * wD[1];
    }
    float inv = (den > 0.f) ? 0.25f / den : 0.f;
    __shared__ float sa_sh[128];
#pragma unroll
    for (int jj = 0; jj < 8; jj++) {
        float s = a[jj] * inv;
        s += __shfl_xor(s, 16);
        s += __shfl_xor(s, 32);
        a[jj] = s;
    }
    if (l < 16) {
#pragma unroll
        for (int jj = 0; jj < 8; jj++) sa_sh[l * 8 + jj] = a[jj];
    }
    __syncthreads();
    f32x2 sa2 = *(const f32x2*)&sa_sh[l * 2];
    ushort2 sk = *(const ushort2*)(nrow + 1536 + l * 4);
    ushort2 gt = *(const ushort2*)(mod + (size_t)node * 768 + 256 + l * 2);
    f32x2 xv2 = *(const f32x2*)(x + (size_t)node * 128 + l * 2);
    float xv0 = xv2[0] + bf2f(gt.x) * (sa2[0] + bf2f(sk.x));
    float xv1 = xv2[1] + bf2f(gt.y) * (sa2[1] + bf2f(sk.y));
    f32x2 xo; xo[0] = xv0; xo[1] = xv1;
    *(f32x2*)(x1 + (size_t)node * 128 + l * 2) = xo;
    float s = xv0 + xv1, ssq = xv0 * xv0 + xv1 * xv1;
#pragma unroll
    for (int m = 1; m < 64; m <<= 1) { s += __shfl_xor(s, m); ssq += __shfl_xor(ssq, m); }
    float mu = s * (1.f / 128.f);
    float rs = rsqrtf(ssq * (1.f / 128.f) - mu * mu + 1e-6f);
    ushort2 qo;
    qo.x = f2bf((xv0 - mu) * rs * n3g[l * 2] + n3b[l * 2]);
    qo.y = f2bf((xv1 - mu) * rs * n3g[l * 2 + 1] + n3b[l * 2 + 1]);
    *(ushort2*)(qn + (size_t)node * 128 + l * 2) = qo;
}

// ---------------------------------------------------------------------------
// Cross-attention middle. qw fp8 in, u bf16 out. te f32 staged in LDS.
// ---------------------------------------------------------------------------
__global__ __launch_bounds__(128) void cross_mid_kernel(
    const float* __restrict__ te, const unsigned char* __restrict__ qw,
    unsigned short* __restrict__ u)
{
    int node = blockIdx.x, t = threadIdx.x;
    __shared__ float tes[32 * 132];
    __shared__ float qws[512];
    __shared__ float attnL[128];
#pragma unroll
    for (int i = 0; i < 8; i++) {
        int f = t + i * 128;
        int l = f >> 5, ii = (f & 31) * 4;
        float4 val = *(const float4*)(te + (size_t)node * 4096 + l * 128 + ii);
        *(float4*)&tes[l * 132 + ii] = val;
    }
    {
        unsigned int qv = *(const unsigned int*)(qw + (size_t)node * 512 + t * 4);
        f32x2 a = __builtin_amdgcn_cvt_pk_f32_fp8(qv, false);
        f32x2 b = __builtin_amdgcn_cvt_pk_f32_fp8(qv, true);
        qws[t * 4 + 0] = a[0];
        qws[t * 4 + 1] = a[1];
        qws[t * 4 + 2] = b[0];
        qws[t * 4 + 3] = b[1];
    }
    __syncthreads();

    int h = t >> 5, l = t & 31;
    float sc = 0.f;
#pragma unroll
    for (int i = 0; i < 32; i++) {
        float4 tv = *(const float4*)&tes[l * 132 + i * 4];
        float4 qv4 = *(const float4*)&qws[h * 128 + i * 4];
        sc += tv.x * qv4.x + tv.y * qv4.y + tv.z * qv4.z + tv.w * qv4.w;
    }
    sc *= 0.17677669529663687f;  // 1/sqrt(32)
    float mx = sc;
#pragma unroll
    for (int mm = 1; mm < 32; mm <<= 1) mx = fmaxf(mx, __shfl_xor(mx, mm));
    float e = __expf(sc - mx);
    float ssum = e;
#pragma unroll
    for (int mm = 1; mm < 32; mm <<= 1) ssum += __shfl_xor(ssum, mm);
    attnL[t] = e / ssum;
    __syncthreads();

    int i0 = t & 31;
    float u0 = 0, u1 = 0, u2 = 0, u3 = 0;
#pragma unroll 4
    for (int ll = 0; ll < 32; ll++) {
        float a = attnL[h * 32 + ll];
        u0 += a * tes[ll * 132 + i0];
        u1 += a * tes[ll * 132 + i0 + 32];
        u2 += a * tes[ll * 132 + i0 + 64];
        u3 += a * tes[ll * 132 + i0 + 96];
    }
    size_t ub = (size_t)node * 512 + h * 128;
    u[ub + i0] = f2bf(u0);
    u[ub + i0 + 32] = f2bf(u1);
    u[ub + i0 + 64] = f2bf(u2);
    u[ub + i0 + 96] = f2bf(u3);
}

// ---------------------------------------------------------------------------
extern "C" void kernel_launch(void* const* d_in, const int* in_sizes, int n_in,
                              void* d_out, int out_size, void* d_ws, size_t ws_size,
                              hipStream_t stream)
{
    const int N = in_sizes[0] / 128;        // 20000
    const int E = in_sizes[1] / 2;          // 320000

    const float* x      = (const float*)d_in[0];
    const int*   ei     = (const int*)d_in[1];
    const float* t_in   = (const float*)d_in[2];
    const float* te     = (const float*)d_in[3];
    const float* sa_q_w = (const float*)d_in[4];
    const float* sa_q_b = (const float*)d_in[5];
    const float* sa_k_w = (const float*)d_in[6];
    const float* sa_k_b = (const float*)d_in[7];
    const float* sa_v_w = (const float*)d_in[8];
    const float* sa_v_b = (const float*)d_in[9];
    const float* sa_skip_w = (const float*)d_in[10];
    const float* sa_skip_b = (const float*)d_in[11];
    const float* n3_g   = (const float*)d_in[12];
    const float* n3_b   = (const float*)d_in[13];
    const float* mha_q_w = (const float*)d_in[14];
    const float* mha_q_b = (const float*)d_in[15];
    const float* mha_k_w = (const float*)d_in[16];
    const float* mha_v_w = (const float*)d_in[18];
    const float* mha_v_b = (const float*)d_in[19];
    const float* mha_o_w = (const float*)d_in[20];
    const float* mha_o_b = (const float*)d_in[21];
    const float* fc1_w  = (const float*)d_in[22];
    const float* fc1_b  = (const float*)d_in[23];
    const float* fc2_w  = (const float*)d_in[24];
    const float* fc2_b  = (const float*)d_in[25];
    const float* ada_w  = (const float*)d_in[26];
    const float* ada_b  = (const float*)d_in[27];
    float* out = (float*)d_out;

    // workspace layout (float units, 16B-aligned throughout)
    float* ws = (float*)d_ws;
    size_t o = 0;
    unsigned short* modb = (unsigned short*)(ws + o); o += (size_t)N * 384; // [N,768] bf16
    unsigned short* Bbuf = (unsigned short*)(ws + o); o += (size_t)N * 64;  // xm/xm2 bf16
    unsigned short* Qn   = (unsigned short*)(ws + o); o += (size_t)N * 64;  // qn bf16
    unsigned char*  Cbuf = (unsigned char*)(ws + o); o += (size_t)N * 128;  // qw fp8 [N,512]
    unsigned short* Dbuf = (unsigned short*)(ws + o); o += (size_t)N * 256; // u bf16
    unsigned short* Ebuf = (unsigned short*)(ws + o); o += (size_t)N * 256; // h bf16 / silu-t
    float* Gbuf = ws + o; o += (size_t)N * 128;                             // x1 -> x2 f32
    unsigned char* QKV = (unsigned char*)(ws + o); o += (size_t)N * (QKV_STRIDE_B / 4);
    unsigned short* Wsa_t  = (unsigned short*)(ws + o); o += 1664 * 128 / 2;
    unsigned short* Mcat_t = (unsigned short*)(ws + o); o += 512 * 128 / 2;
    unsigned short* Pcat_t = (unsigned short*)(ws + o); o += 128 * 512 / 2;
    unsigned short* fc1_t  = (unsigned short*)(ws + o); o += 512 * 128 / 2;
    unsigned short* fc2_t  = (unsigned short*)(ws + o); o += 128 * 512 / 2;
    unsigned short* ada_t  = (unsigned short*)(ws + o); o += 768 * 128 / 2;
    float* bsa   = ws + o; o += 1664;
    float* biasM = ws + o; o += 512;
    float* co    = ws + o; o += 128;
    int* count   = (int*)(ws + o); o += N;
    int* base    = (int*)(ws + o); o += N + 4;
    int* cursor  = (int*)(ws + o); o += N;
    int* csr_src = (int*)(ws + o); o += E;

    unsigned short* Tbuf = Ebuf;   // silu(t) bf16, dead before fc1 writes Ebuf

    const int* src = ei;
    const int* dst = ei + E;
    const int rb128 = (N + 127) / 128;   // 157
    const int rb64  = (N + 63) / 64;     // 313
    const int n8 = N * 16;
    const int prepBlocks = 1984 + (n8 + 255) / 256;

    // ---- weight prep + silu(t) ----
    prep_all<<<prepBlocks, 256, 0, stream>>>(sa_q_w, sa_q_b, sa_k_w, sa_k_b,
                                             sa_v_w, sa_v_b, sa_skip_w, sa_skip_b,
                                             fc1_w, fc2_w, ada_w,
                                             Wsa_t, bsa, fc1_t, fc2_t, ada_t,
                                             mha_q_w, mha_q_b, mha_k_w, mha_v_w,
                                             mha_v_b, mha_o_w, mha_o_b,
                                             Mcat_t, biasM, Pcat_t, co,
                                             t_in, Tbuf, n8);

    // ---- CSR build ----
    hipMemsetAsync(count, 0, (size_t)N * sizeof(int), stream);
    count_edges<<<(E + 255) / 256, 256, 0, stream>>>(dst, count, E);
    scan_all<<<1, 1024, 0, stream>>>(count, base, cursor, N);
    scatter_edges<<<(E + 255) / 256, 256, 0, stream>>>(src, dst, cursor, csr_src, E);

    // ---- adaLN: mod = silu(t) @ ada_w + ada_b  (bf16 out) ----
    gemm_mfma<4, 0, 1><<<dim3(6, rb128), 256, 0, stream>>>(
        Tbuf, ada_t, ada_b, modb, nullptr, nullptr, nullptr, N, 128, 768);

    // ---- xm = modulate(ln(x), shift_msa, scale_msa) ----
    ln_mod_kernel<<<(N + 3) / 4, 256, 0, stream>>>(x, modb, 0, 128, Bbuf, N);

    // ---- fused q|kv|skip GEMM -> packed QKV (q,kv fp8) ----
    gemm_mfma<4, 4, 1><<<dim3(13, rb128), 256, 0, stream>>>(
        Bbuf, Wsa_t, bsa, QKV, nullptr, nullptr, nullptr, N, 128, 1664);

    // ---- graph attention + residual + fused norm3 -> x1 (f32), qn (bf16) ----
    sa_node_kernel<<<N, 64, 0, stream>>>(QKV, base, csr_src, x, modb,
                                         n3_g, n3_b, Gbuf, Qn);

    // ---- cross attention (folded): qw fp8 ----
    gemm_mfma<4, 6, 0><<<dim3(4, rb128), 256, 0, stream>>>(
        Qn, Mcat_t, biasM, Cbuf, nullptr, nullptr, nullptr, N, 128, 512);
    cross_mid_kernel<<<N, 128, 0, stream>>>(te, Cbuf, Dbuf);
    // x2 = x1 + u@Pcat + co; fused MLP LN+modulate -> Bbuf (xm2)  [PIPE]
    gemm_mfma<2, 5, 0, 1><<<dim3(1, rb64), 256, 0, stream>>>(
        Dbuf, Pcat_t, co, Gbuf, Gbuf, modb, Bbuf, N, 512, 128);

    // ---- MLP ----
    gemm_mfma<4, 1, 1><<<dim3(4, rb128), 256, 0, stream>>>(
        Bbuf, fc1_t, fc1_b, Ebuf, nullptr, nullptr, nullptr, N, 128, 512);
    gemm_mfma<2, 3, 0, 1><<<dim3(1, rb64), 256, 0, stream>>>(
        Ebuf, fc2_t, fc2_b, out, Gbuf, modb + 640, nullptr, N, 512, 128);
}

// Round 12
// 354.557 us; speedup vs baseline: 1.0857x; 1.0857x over previous
//
#include <hip/hip_runtime.h>
#include <hip/hip_bf16.h>
#include <math.h>

using ushort8 = __attribute__((ext_vector_type(8))) unsigned short;
using short8  = __attribute__((ext_vector_type(8))) short;
using f32x4   = __attribute__((ext_vector_type(4))) float;
using f32x2   = __attribute__((ext_vector_type(2))) float;

__device__ __forceinline__ float bf2f(unsigned short u) {
    union { unsigned int i; float f; } c; c.i = ((unsigned int)u) << 16; return c.f;
}
__device__ __forceinline__ unsigned short f2bf(float f) {
    __hip_bfloat16 h = __float2bfloat16(f);
    return *reinterpret_cast<unsigned short*>(&h);
}
__device__ __forceinline__ unsigned char f2fp8(float f) {
    int p = __builtin_amdgcn_cvt_pk_fp8_f32(f, 0.f, 0, false);
    return (unsigned char)(p & 0xff);
}
__device__ __forceinline__ float silu_f(float x) { return x / (1.f + __expf(-x)); }
__device__ __forceinline__ float gelu_f(float x) {
    float x3 = x * x * x;
    return 0.5f * x * (1.f + tanhf(0.7978845608028654f * (x + 0.044715f * x3)));
}

// QKV packed row: 1792 bytes = q[512] fp8 | kv[1024] fp8 | skip[128] bf16
constexpr int QKV_STRIDE_B = 1792;

// ---------------------------------------------------------------------------
// Async global->LDS tile stage with pre-swizzled global source (m173 pattern).
// ---------------------------------------------------------------------------
__device__ __forceinline__ void stage_tile_async(
    const unsigned short* __restrict__ gbase,   // points at (row 0, k0)
    int K, unsigned short (*lds)[64], int nrows, int wid, int lane)
{
    int nch = nrows >> 3;
#pragma unroll
    for (int c = wid; c < nch; c += 4) {
        int n0 = c * 8;
        int n = n0 + (lane >> 3);
        int b = (lane & 7) ^ (n & 7);
        const unsigned short* src = gbase + (size_t)n * K + b * 8;
        __builtin_amdgcn_global_load_lds(
            (const __attribute__((address_space(1))) unsigned int*)src,
            (__attribute__((address_space(3))) unsigned int*)&lds[n0][0],
            16, 0, 0);
    }
}

// ---------------------------------------------------------------------------
// bf16 MFMA GEMM: C = epi(A @ Wt^T + bias)   [BK=64 loop, A bf16, async stage]
// Grid: dim3(M/128, rowBlocks); bijective chunked XCD swizzle.
// EPI: 0=none 1=gelu 2=res+val 3=res+gate*val 4=qkv pack 5=res+val + fused
//      LN+modulate -> out2 bf16   6=fp8 out
// ---------------------------------------------------------------------------
template<int WM, int EPI, int OUTBF>
__global__ __launch_bounds__(256) void gemm_mfma(
    const void* __restrict__ Ain, const unsigned short* __restrict__ Wt,
    const float* __restrict__ bias, void* __restrict__ Cout,
    const float* __restrict__ res, const void* __restrict__ gatep,
    void* __restrict__ out2, int Nrows, int K, int M)
{
    constexpr int BM = 32 * WM;
    __shared__ unsigned short As[BM][64];
    __shared__ unsigned short Bs[128][64];
    const int tid = threadIdx.x;
    const int gx = gridDim.x;
    const int T = gx * gridDim.y;
    const int hw = blockIdx.y * gx + blockIdx.x;
    const int q = T >> 3, r = T & 7, xc = hw & 7, j = hw >> 3;
    const int work = (xc < r ? xc * (q + 1) : r * (q + 1) + (xc - r) * q) + j;
    const int row0 = (work / gx) * BM;
    const int col0 = (work % gx) * 128;
    const int lane = tid & 63;
    const int wid  = tid >> 6;
    const int wr = (wid >> 1) * 16 * WM;
    const int wc = (wid & 1) * 64;
    const int lr = lane & 15;
    const int lk = lane >> 4;

    f32x4 acc[WM][4];
#pragma unroll
    for (int i = 0; i < WM; i++)
#pragma unroll
        for (int jj = 0; jj < 4; jj++) acc[i][jj] = (f32x4)0.f;

    for (int k0 = 0; k0 < K; k0 += 64) {
        stage_tile_async((const unsigned short*)Ain + (size_t)row0 * K + k0,
                         K, As, BM, wid, lane);
        stage_tile_async(Wt + (size_t)col0 * K + k0, K, Bs, 128, wid, lane);
        __syncthreads();

        short8 afr[WM][2], bfr[4][2];
#pragma unroll
        for (int fr = 0; fr < WM; fr++)
#pragma unroll
            for (int s = 0; s < 2; s++) {
                int m = wr + fr * 16 + lr;
                int blk = (s * 4 + lk) ^ (m & 7);
                afr[fr][s] = *(const short8*)&As[m][blk * 8];
            }
#pragma unroll
        for (int fc = 0; fc < 4; fc++)
#pragma unroll
            for (int s = 0; s < 2; s++) {
                int n = wc + fc * 16 + lr;
                int blk = (s * 4 + lk) ^ (n & 7);
                bfr[fc][s] = *(const short8*)&Bs[n][blk * 8];
            }
#pragma unroll
        for (int fr = 0; fr < WM; fr++)
#pragma unroll
            for (int fc = 0; fc < 4; fc++)
#pragma unroll
                for (int s = 0; s < 2; s++)
                    acc[fr][fc] = __builtin_amdgcn_mfma_f32_16x16x32_bf16(
                        afr[fr][s], bfr[fc][s], acc[fr][fc], 0, 0, 0);
        __syncthreads();
    }

#pragma unroll
    for (int fr = 0; fr < WM; fr++) {
#pragma unroll
        for (int fc = 0; fc < 4; fc++) {
#pragma unroll
            for (int rr = 0; rr < 4; rr++) {
                int lrow = wr + fr * 16 + (lane >> 4) * 4 + rr;
                int row = row0 + lrow;
                if (row >= Nrows) continue;
                int col = col0 + wc + fc * 16 + (lane & 15);
                float val = acc[fr][fc][rr] + bias[col];
                if (EPI == 4) {
                    unsigned char* rowp = (unsigned char*)Cout + (size_t)row * QKV_STRIDE_B;
                    if (col < 1536) {
                        rowp[col] = f2fp8(val);            // q fp8 | kv fp8
                    } else {
                        *(unsigned short*)(rowp + 1536 + 2 * (col - 1536)) = f2bf(val);
                    }
                } else if (EPI == 5) {
                    size_t idx = (size_t)row * M + col;
                    float x2 = res[idx] + val;
                    ((float*)Cout)[idx] = x2;
                    (&Bs[0][0])[lrow * 128 + col - col0] = f2bf(x2);
                } else if (EPI == 6) {
                    ((unsigned char*)Cout)[(size_t)row * M + col] = f2fp8(val);
                } else {
                    size_t idx = (size_t)row * M + col;
                    if (EPI == 1) val = gelu_f(val);
                    else if (EPI == 2) val = res[idx] + val;
                    else if (EPI == 3) val = res[idx] +
                        bf2f(((const unsigned short*)gatep)[(size_t)row * 768 + col]) * val;
                    if (OUTBF) ((unsigned short*)Cout)[idx] = f2bf(val);
                    else       ((float*)Cout)[idx] = val;
                }
            }
        }
    }

    if constexpr (EPI == 5) {
        __syncthreads();
        const unsigned short* x2b = &Bs[0][0];
        const unsigned short* mod = (const unsigned short*)gatep;
        for (int rr = wid; rr < BM; rr += 4) {
            int row = row0 + rr;
            if (row >= Nrows) continue;
            ushort2 xv = *(const ushort2*)&x2b[rr * 128 + lane * 2];
            float v0 = bf2f(xv.x), v1 = bf2f(xv.y);
            float s = v0 + v1, ss = v0 * v0 + v1 * v1;
#pragma unroll
            for (int mm = 1; mm < 64; mm <<= 1) {
                s += __shfl_xor(s, mm); ss += __shfl_xor(ss, mm);
            }
            float mu = s * (1.f / 128.f);
            float rs = rsqrtf(ss * (1.f / 128.f) - mu * mu + 1e-6f);
            const unsigned short* mp = mod + (size_t)row * 768;
            ushort2 sh = *(const ushort2*)(mp + 384 + lane * 2);
            ushort2 sc = *(const ushort2*)(mp + 512 + lane * 2);
            ushort2 o;
            o.x = f2bf((v0 - mu) * rs * (1.f + bf2f(sc.x)) + bf2f(sh.x));
            o.y = f2bf((v1 - mu) * rs * (1.f + bf2f(sc.y)) + bf2f(sh.y));
            *(ushort2*)((unsigned short*)out2 + (size_t)row * 128 + lane * 2) = o;
        }
    }
}

// ---------------------------------------------------------------------------
// ALL weight prep + silu(t)->bf16 in ONE kernel.
// ---------------------------------------------------------------------------
__global__ __launch_bounds__(256) void prep_all(
    const float* __restrict__ qW, const float* __restrict__ qB,
    const float* __restrict__ kW, const float* __restrict__ kB,
    const float* __restrict__ vW, const float* __restrict__ vB,
    const float* __restrict__ sW, const float* __restrict__ sB,
    const float* __restrict__ f1W, const float* __restrict__ f2W,
    const float* __restrict__ adW,
    unsigned short* __restrict__ Wsa_t, float* __restrict__ bsa,
    unsigned short* __restrict__ fc1_t, unsigned short* __restrict__ fc2_t,
    unsigned short* __restrict__ ada_t,
    const float* __restrict__ Wq, const float* __restrict__ bq,
    const float* __restrict__ Wk, const float* __restrict__ Wv,
    const float* __restrict__ bv, const float* __restrict__ Wo,
    const float* __restrict__ bo,
    unsigned short* __restrict__ Mcat_t, float* __restrict__ biasM,
    unsigned short* __restrict__ Pcat_t, float* __restrict__ co,
    const float* __restrict__ t_in, unsigned short* __restrict__ Tbuf, int n8)
{
    int g = blockIdx.x * 256 + threadIdx.x;
    if (g < 65536) {                       // sa_q
        int m = g >> 7, kk = g & 127;
        Wsa_t[m * 128 + kk] = f2bf(qW[(size_t)kk * 512 + m]);
        if (kk == 0) bsa[m] = qB[m];
    } else if (g < 131072) {               // sa_k (lane-16B layout)
        int l = g - 65536; int m = l >> 7, kk = l & 127;
        int h = m >> 7, dl = m & 127;
        int p = 512 + h * 256 + ((dl >> 3) << 4) + (dl & 7);
        Wsa_t[p * 128 + kk] = f2bf(kW[(size_t)kk * 512 + m]);
        if (kk == 0) bsa[p] = kB[m];
    } else if (g < 196608) {               // sa_v (lane-16B layout)
        int l = g - 131072; int m = l >> 7, kk = l & 127;
        int h = m >> 7, dl = m & 127;
        int p = 512 + h * 256 + ((dl >> 3) << 4) + 8 + (dl & 7);
        Wsa_t[p * 128 + kk] = f2bf(vW[(size_t)kk * 512 + m]);
        if (kk == 0) bsa[p] = vB[m];
    } else if (g < 212992) {               // sa_skip
        int l = g - 196608; int m = l >> 7, kk = l & 127;
        Wsa_t[(1536 + m) * 128 + kk] = f2bf(sW[(size_t)kk * 128 + m]);
        if (kk == 0) bsa[1536 + m] = sB[m];
    } else if (g < 278528) {               // fc1
        int l = g - 212992; int m = l >> 7, kk = l & 127;
        fc1_t[m * 128 + kk] = f2bf(f1W[(size_t)kk * 512 + m]);
    } else if (g < 344064) {               // fc2
        int l = g - 278528; int m = l >> 9, kk = l & 511;
        fc2_t[m * 512 + kk] = f2bf(f2W[(size_t)kk * 128 + m]);
    } else if (g < 442368) {               // ada
        int l = g - 344064; int m = l >> 7, kk = l & 127;
        ada_t[m * 128 + kk] = f2bf(adW[(size_t)kk * 768 + m]);
    } else if (g < 507904) {               // folded cross-attn weights
        int g2 = g - 442368;               // 0..65535
        {
            int i0 = g2 >> 9, col = g2 & 511, h = col >> 7, i = col & 127;
            float s = 0.f;
#pragma unroll 8
            for (int jj = 0; jj < 32; jj++)
                s += Wq[i0 * 128 + h * 32 + jj] * Wk[i * 128 + h * 32 + jj];
            Mcat_t[col * 128 + i0] = f2bf(s);
        }
        {
            int rowp = g2 >> 7, jc = g2 & 127, h = rowp >> 7, i = rowp & 127;
            float s = 0.f;
#pragma unroll 8
            for (int d = 0; d < 32; d++)
                s += Wv[i * 128 + h * 32 + d] * Wo[(h * 32 + d) * 128 + jc];
            Pcat_t[jc * 512 + rowp] = f2bf(s);
        }
        if (g2 < 512) {
            int h = g2 >> 7, i = g2 & 127;
            float s = 0.f;
            for (int jj = 0; jj < 32; jj++)
                s += bq[h * 32 + jj] * Wk[i * 128 + h * 32 + jj];
            biasM[g2] = s;
        }
        if (g2 < 128) {
            float s = bo[g2];
            for (int m = 0; m < 128; m++) s += bv[m] * Wo[m * 128 + g2];
            co[g2] = s;
        }
    } else {                               // silu(t) -> bf16, 8 elems/thread
        int i = g - 507904;
        if (i < n8) {
            const float* p = t_in + (size_t)i * 8;
            float4 a = *(const float4*)p, b = *(const float4*)(p + 4);
            float v[8] = {a.x, a.y, a.z, a.w, b.x, b.y, b.z, b.w};
            ushort8 h;
#pragma unroll
            for (int jj = 0; jj < 8; jj++) h[jj] = f2bf(silu_f(v[jj]));
            *(ushort8*)(Tbuf + (size_t)i * 8) = h;
        }
    }
}

// ---------------------------------------------------------------------------
// LN + modulate, one WAVE per node (xm for the QKV projection).
// ---------------------------------------------------------------------------
__global__ __launch_bounds__(256) void ln_mod_kernel(
    const float* __restrict__ x, const unsigned short* __restrict__ mod,
    int shift_off, int scale_off, unsigned short* __restrict__ outb, int N)
{
    int node = blockIdx.x * 4 + (threadIdx.x >> 6);
    if (node >= N) return;
    int lane = threadIdx.x & 63;
    f32x2 v = *(const f32x2*)(x + (size_t)node * 128 + lane * 2);
    float s = v[0] + v[1], ss = v[0] * v[0] + v[1] * v[1];
#pragma unroll
    for (int m = 1; m < 64; m <<= 1) { s += __shfl_xor(s, m); ss += __shfl_xor(ss, m); }
    float mu = s * (1.f / 128.f);
    float rs = rsqrtf(ss * (1.f / 128.f) - mu * mu + 1e-6f);
    const unsigned short* mp = mod + (size_t)node * 768;
    ushort2 sh = *(const ushort2*)(mp + shift_off + lane * 2);
    ushort2 sc = *(const ushort2*)(mp + scale_off + lane * 2);
    ushort2 o;
    o.x = f2bf((v[0] - mu) * rs * (1.f + bf2f(sc.x)) + bf2f(sh.x));
    o.y = f2bf((v[1] - mu) * rs * (1.f + bf2f(sc.y)) + bf2f(sh.y));
    *(ushort2*)(outb + (size_t)node * 128 + lane * 2) = o;
}

// ---------------------------------------------------------------------------
// CSR build
// ---------------------------------------------------------------------------
__global__ void count_edges(const int* __restrict__ dst, int* __restrict__ count, int E) {
    int e = blockIdx.x * blockDim.x + threadIdx.x;
    if (e < E) atomicAdd(&count[dst[e]], 1);
}

// shfl-based inclusive scan: 16 waves, 2 barriers
__global__ __launch_bounds__(1024) void scan_block(const int* __restrict__ cnt,
                                                   int* __restrict__ pre,
                                                   int* __restrict__ bsum, int n)
{
    int gid = blockIdx.x * 1024 + threadIdx.x;
    int lane = threadIdx.x & 63, w = threadIdx.x >> 6;
    int s = (gid < n) ? cnt[gid] : 0;
#pragma unroll
    for (int off = 1; off < 64; off <<= 1) {
        int t = __shfl_up(s, off);
        if (lane >= off) s += t;
    }
    __shared__ int wsum[16];
    if (lane == 63) wsum[w] = s;
    __syncthreads();
    if (w == 0 && lane < 16) {
        int wsv = wsum[lane];
#pragma unroll
        for (int off = 1; off < 16; off <<= 1) {
            int t = __shfl_up(wsv, off);
            if (lane >= off) wsv += t;
        }
        wsum[lane] = wsv;
    }
    __syncthreads();
    if (w > 0) s += wsum[w - 1];
    if (gid < n) pre[gid] = s;
    if (threadIdx.x == 1023) bsum[blockIdx.x] = s;
}

__global__ void scan_fix(const int* __restrict__ pre, const int* __restrict__ bsum,
                         const int* __restrict__ cnt,
                         int* __restrict__ base, int* __restrict__ cursor,
                         int n, int nb)
{
    __shared__ int boff[32];
    if (threadIdx.x == 0) {
        int c = 0;
        for (int i = 0; i < nb; i++) { boff[i] = c; c += bsum[i]; }
    }
    __syncthreads();
    int gid = blockIdx.x * 256 + threadIdx.x;
    if (gid < n) {
        int inc = pre[gid] + boff[gid >> 10];
        base[gid + 1] = inc;
        cursor[gid] = inc - cnt[gid];
    }
    if (gid == 0) base[0] = 0;
}

__global__ void scatter_edges(const int* __restrict__ src, const int* __restrict__ dst,
                              int* __restrict__ cursor, int* __restrict__ csr_src, int E) {
    int e = blockIdx.x * blockDim.x + threadIdx.x;
    if (e < E) {
        int pos = atomicAdd(&cursor[dst[e]], 1);
        csr_src[pos] = src[e];
    }
}

// ---------------------------------------------------------------------------
// Graph self-attention + residual + fused norm3 LN. ONE WAVE per node.
// q fp8 (bytes l*8..+7), kv fp8 (512 + l*16), skip bf16 (1536 + 2*dim).
// ---------------------------------------------------------------------------
__global__ __launch_bounds__(64) void sa_node_kernel(
    const unsigned char* __restrict__ qkv,
    const int* __restrict__ base, const int* __restrict__ csr_src,
    const float* __restrict__ x, const unsigned short* __restrict__ mod,
    const float* __restrict__ n3g, const float* __restrict__ n3b,
    float* __restrict__ x1, unsigned short* __restrict__ qn)
{
    int node = blockIdx.x, l = threadIdx.x;
    const unsigned char* nrow = qkv + (size_t)node * QKV_STRIDE_B;
    uint2 qb = *(const uint2*)(nrow + l * 8);
    const float scl = 0.08838834764831845f;          // 1/sqrt(128)
    float q[8];
    {
        f32x2 qA = __builtin_amdgcn_cvt_pk_f32_fp8(qb.x, false);
        f32x2 qB = __builtin_amdgcn_cvt_pk_f32_fp8(qb.x, true);
        f32x2 qC = __builtin_amdgcn_cvt_pk_f32_fp8(qb.y, false);
        f32x2 qD = __builtin_amdgcn_cvt_pk_f32_fp8(qb.y, true);
        q[0] = qA[0] * scl; q[1] = qA[1] * scl;
        q[2] = qB[0] * scl; q[3] = qB[1] * scl;
        q[4] = qC[0] * scl; q[5] = qC[1] * scl;
        q[6] = qD[0] * scl; q[7] = qD[1] * scl;
    }
    int beg = base[node], end = base[node + 1];
    float den = 0.f;
    float a[8];
#pragma unroll
    for (int jj = 0; jj < 8; jj++) a[jj] = 0.f;
    uint4 c0 = make_uint4(0, 0, 0, 0), c1 = c0;
    if (beg < end)
        c0 = *(const uint4*)(qkv + (size_t)csr_src[beg] * QKV_STRIDE_B + 512 + l * 16);
    if (beg + 1 < end)
        c1 = *(const uint4*)(qkv + (size_t)csr_src[beg + 1] * QKV_STRIDE_B + 512 + l * 16);
    for (int e = beg; e < end; e += 2) {
        uint4 m0 = c0, m1 = c1;
        if (e + 2 < end)
            c0 = *(const uint4*)(qkv + (size_t)csr_src[e + 2] * QKV_STRIDE_B + 512 + l * 16);
        if (e + 3 < end)
            c1 = *(const uint4*)(qkv + (size_t)csr_src[e + 3] * QKV_STRIDE_B + 512 + l * 16);
        f32x2 kA, kB, kC, kD;
        kA = __builtin_amdgcn_cvt_pk_f32_fp8(m0.x, false);
        kB = __builtin_amdgcn_cvt_pk_f32_fp8(m0.x, true);
        kC = __builtin_amdgcn_cvt_pk_f32_fp8(m0.y, false);
        kD = __builtin_amdgcn_cvt_pk_f32_fp8(m0.y, true);
        float p0 = q[0]*kA[0] + q[1]*kA[1] + q[2]*kB[0] + q[3]*kB[1]
                 + q[4]*kC[0] + q[5]*kC[1] + q[6]*kD[0] + q[7]*kD[1];
        kA = __builtin_amdgcn_cvt_pk_f32_fp8(m1.x, false);
        kB = __builtin_amdgcn_cvt_pk_f32_fp8(m1.x, true);
        kC = __builtin_amdgcn_cvt_pk_f32_fp8(m1.y, false);
        kD = __builtin_amdgcn_cvt_pk_f32_fp8(m1.y, true);
        float p1 = q[0]*kA[0] + q[1]*kA[1] + q[2]*kB[0] + q[3]*kB[1]
                 + q[4]*kC[0] + q[5]*kC[1] + q[6]*kD[0] + q[7]*kD[1];
#pragma unroll
        for (int mm = 1; mm < 16; mm <<= 1) {
            p0 += __shfl_xor(p0, mm);
            p1 += __shfl_xor(p1, mm);
        }
        float pe0 = __expf(fminf(p0, 80.f));
        float pe1 = (e + 1 < end) ? __expf(fminf(p1, 80.f)) : 0.f;
        den += pe0 + pe1;
        f32x2 vA, vB, vC, vD, wA, wB, wC, wD;
        vA = __builtin_amdgcn_cvt_pk_f32_fp8(m0.z, false);
        vB = __builtin_amdgcn_cvt_pk_f32_fp8(m0.z, true);
        vC = __builtin_amdgcn_cvt_pk_f32_fp8(m0.w, false);
        vD = __builtin_amdgcn_cvt_pk_f32_fp8(m0.w, true);
        wA = __builtin_amdgcn_cvt_pk_f32_fp8(m1.z, false);
        wB = __builtin_amdgcn_cvt_pk_f32_fp8(m1.z, true);
        wC = __builtin_amdgcn_cvt_pk_f32_fp8(m1.w, false);
        wD = __builtin_amdgcn_cvt_pk_f32_fp8(m1.w, true);
        a[0] += pe0 * vA[0] + pe1 * wA[0];
        a[1] += pe0 * vA[1] + pe1 * wA[1];
        a[2] += pe0 * vB[0] + pe1 * wB[0];
        a[3] += pe0 * vB[1] + pe1 * wB[1];
        a[4] += pe0 * vC[0] + pe1 * wC[0];
        a[5] += pe0 * vC[1] + pe1 * wC[1];
        a[6] += pe0 * vD[0] + pe1 * wD[0];
        a[7] += pe0 * vD[1] + pe1 * wD[1];
    }
    float inv = (den > 0.f) ? 0.25f / den : 0.f;
    __shared__ float sa_sh[128];
#pragma unroll
    for (int jj = 0; jj < 8; jj++) {
        float s = a[jj] * inv;
        s += __shfl_xor(s, 16);
        s += __shfl_xor(s, 32);
        a[jj] = s;
    }
    if (l < 16) {
#pragma unroll
        for (int jj = 0; jj < 8; jj++) sa_sh[l * 8 + jj] = a[jj];
    }
    __syncthreads();
    f32x2 sa2 = *(const f32x2*)&sa_sh[l * 2];
    ushort2 sk = *(const ushort2*)(nrow + 1536 + l * 4);
    ushort2 gt = *(const ushort2*)(mod + (size_t)node * 768 + 256 + l * 2);
    f32x2 xv2 = *(const f32x2*)(x + (size_t)node * 128 + l * 2);
    float xv0 = xv2[0] + bf2f(gt.x) * (sa2[0] + bf2f(sk.x));
    float xv1 = xv2[1] + bf2f(gt.y) * (sa2[1] + bf2f(sk.y));
    f32x2 xo; xo[0] = xv0; xo[1] = xv1;
    *(f32x2*)(x1 + (size_t)node * 128 + l * 2) = xo;
    float s = xv0 + xv1, ssq = xv0 * xv0 + xv1 * xv1;
#pragma unroll
    for (int m = 1; m < 64; m <<= 1) { s += __shfl_xor(s, m); ssq += __shfl_xor(ssq, m); }
    float mu = s * (1.f / 128.f);
    float rs = rsqrtf(ssq * (1.f / 128.f) - mu * mu + 1e-6f);
    ushort2 qo;
    qo.x = f2bf((xv0 - mu) * rs * n3g[l * 2] + n3b[l * 2]);
    qo.y = f2bf((xv1 - mu) * rs * n3g[l * 2 + 1] + n3b[l * 2 + 1]);
    *(ushort2*)(qn + (size_t)node * 128 + l * 2) = qo;
}

// ---------------------------------------------------------------------------
// Cross-attention middle. qw fp8 in, u bf16 out. te f32 staged in LDS.
// ---------------------------------------------------------------------------
__global__ __launch_bounds__(128) void cross_mid_kernel(
    const float* __restrict__ te, const unsigned char* __restrict__ qw,
    unsigned short* __restrict__ u)
{
    int node = blockIdx.x, t = threadIdx.x;
    __shared__ float tes[32 * 132];
    __shared__ float qws[512];
    __shared__ float attnL[128];
#pragma unroll
    for (int i = 0; i < 8; i++) {
        int f = t + i * 128;
        int l = f >> 5, ii = (f & 31) * 4;
        float4 val = *(const float4*)(te + (size_t)node * 4096 + l * 128 + ii);
        *(float4*)&tes[l * 132 + ii] = val;
    }
    {
        unsigned int qv = *(const unsigned int*)(qw + (size_t)node * 512 + t * 4);
        f32x2 a = __builtin_amdgcn_cvt_pk_f32_fp8(qv, false);
        f32x2 b = __builtin_amdgcn_cvt_pk_f32_fp8(qv, true);
        qws[t * 4 + 0] = a[0];
        qws[t * 4 + 1] = a[1];
        qws[t * 4 + 2] = b[0];
        qws[t * 4 + 3] = b[1];
    }
    __syncthreads();

    int h = t >> 5, l = t & 31;
    float sc = 0.f;
#pragma unroll
    for (int i = 0; i < 32; i++) {
        float4 tv = *(const float4*)&tes[l * 132 + i * 4];
        float4 qv4 = *(const float4*)&qws[h * 128 + i * 4];
        sc += tv.x * qv4.x + tv.y * qv4.y + tv.z * qv4.z + tv.w * qv4.w;
    }
    sc *= 0.17677669529663687f;  // 1/sqrt(32)
    float mx = sc;
#pragma unroll
    for (int mm = 1; mm < 32; mm <<= 1) mx = fmaxf(mx, __shfl_xor(mx, mm));
    float e = __expf(sc - mx);
    float ssum = e;
#pragma unroll
    for (int mm = 1; mm < 32; mm <<= 1) ssum += __shfl_xor(ssum, mm);
    attnL[t] = e / ssum;
    __syncthreads();

    int i0 = t & 31;
    float u0 = 0, u1 = 0, u2 = 0, u3 = 0;
#pragma unroll 4
    for (int ll = 0; ll < 32; ll++) {
        float a = attnL[h * 32 + ll];
        u0 += a * tes[ll * 132 + i0];
        u1 += a * tes[ll * 132 + i0 + 32];
        u2 += a * tes[ll * 132 + i0 + 64];
        u3 += a * tes[ll * 132 + i0 + 96];
    }
    size_t ub = (size_t)node * 512 + h * 128;
    u[ub + i0] = f2bf(u0);
    u[ub + i0 + 32] = f2bf(u1);
    u[ub + i0 + 64] = f2bf(u2);
    u[ub + i0 + 96] = f2bf(u3);
}

// ---------------------------------------------------------------------------
extern "C" void kernel_launch(void* const* d_in, const int* in_sizes, int n_in,
                              void* d_out, int out_size, void* d_ws, size_t ws_size,
                              hipStream_t stream)
{
    const int N = in_sizes[0] / 128;        // 20000
    const int E = in_sizes[1] / 2;          // 320000

    const float* x      = (const float*)d_in[0];
    const int*   ei     = (const int*)d_in[1];
    const float* t_in   = (const float*)d_in[2];
    const float* te     = (const float*)d_in[3];
    const float* sa_q_w = (const float*)d_in[4];
    const float* sa_q_b = (const float*)d_in[5];
    const float* sa_k_w = (const float*)d_in[6];
    const float* sa_k_b = (const float*)d_in[7];
    const float* sa_v_w = (const float*)d_in[8];
    const float* sa_v_b = (const float*)d_in[9];
    const float* sa_skip_w = (const float*)d_in[10];
    const float* sa_skip_b = (const float*)d_in[11];
    const float* n3_g   = (const float*)d_in[12];
    const float* n3_b   = (const float*)d_in[13];
    const float* mha_q_w = (const float*)d_in[14];
    const float* mha_q_b = (const float*)d_in[15];
    const float* mha_k_w = (const float*)d_in[16];
    const float* mha_v_w = (const float*)d_in[18];
    const float* mha_v_b = (const float*)d_in[19];
    const float* mha_o_w = (const float*)d_in[20];
    const float* mha_o_b = (const float*)d_in[21];
    const float* fc1_w  = (const float*)d_in[22];
    const float* fc1_b  = (const float*)d_in[23];
    const float* fc2_w  = (const float*)d_in[24];
    const float* fc2_b  = (const float*)d_in[25];
    const float* ada_w  = (const float*)d_in[26];
    const float* ada_b  = (const float*)d_in[27];
    float* out = (float*)d_out;

    // workspace layout (float units, 16B-aligned throughout)
    float* ws = (float*)d_ws;
    size_t o = 0;
    unsigned short* modb = (unsigned short*)(ws + o); o += (size_t)N * 384; // [N,768] bf16
    unsigned short* Bbuf = (unsigned short*)(ws + o); o += (size_t)N * 64;  // xm/xm2 bf16
    unsigned short* Qn   = (unsigned short*)(ws + o); o += (size_t)N * 64;  // qn bf16
    unsigned char*  Cbuf = (unsigned char*)(ws + o); o += (size_t)N * 128;  // qw fp8 [N,512]
    unsigned short* Dbuf = (unsigned short*)(ws + o); o += (size_t)N * 256; // u bf16
    unsigned short* Ebuf = (unsigned short*)(ws + o); o += (size_t)N * 256; // h bf16 / silu-t
    float* Gbuf = ws + o; o += (size_t)N * 128;                             // x1 -> x2 f32
    unsigned char* QKV = (unsigned char*)(ws + o); o += (size_t)N * (QKV_STRIDE_B / 4);
    unsigned short* Wsa_t  = (unsigned short*)(ws + o); o += 1664 * 128 / 2;
    unsigned short* Mcat_t = (unsigned short*)(ws + o); o += 512 * 128 / 2;
    unsigned short* Pcat_t = (unsigned short*)(ws + o); o += 128 * 512 / 2;
    unsigned short* fc1_t  = (unsigned short*)(ws + o); o += 512 * 128 / 2;
    unsigned short* fc2_t  = (unsigned short*)(ws + o); o += 128 * 512 / 2;
    unsigned short* ada_t  = (unsigned short*)(ws + o); o += 768 * 128 / 2;
    float* bsa   = ws + o; o += 1664;
    float* biasM = ws + o; o += 512;
    float* co    = ws + o; o += 128;
    int* count   = (int*)(ws + o); o += N;
    int* base    = (int*)(ws + o); o += N + 4;
    int* cursor  = (int*)(ws + o); o += N;
    int* pre     = (int*)(ws + o); o += N;
    int* bsum    = (int*)(ws + o); o += 32;
    int* csr_src = (int*)(ws + o); o += E;

    unsigned short* Tbuf = Ebuf;   // silu(t) bf16, dead before fc1 writes Ebuf

    const int* src = ei;
    const int* dst = ei + E;
    const int rb128 = (N + 127) / 128;   // 157
    const int rb64  = (N + 63) / 64;     // 313
    const int nScan = (N + 1023) / 1024;
    const int n8 = N * 16;
    const int prepBlocks = 1984 + (n8 + 255) / 256;

    // ---- weight prep + silu(t) ----
    prep_all<<<prepBlocks, 256, 0, stream>>>(sa_q_w, sa_q_b, sa_k_w, sa_k_b,
                                             sa_v_w, sa_v_b, sa_skip_w, sa_skip_b,
                                             fc1_w, fc2_w, ada_w,
                                             Wsa_t, bsa, fc1_t, fc2_t, ada_t,
                                             mha_q_w, mha_q_b, mha_k_w, mha_v_w,
                                             mha_v_b, mha_o_w, mha_o_b,
                                             Mcat_t, biasM, Pcat_t, co,
                                             t_in, Tbuf, n8);

    // ---- CSR build ----
    hipMemsetAsync(count, 0, (size_t)N * sizeof(int), stream);
    count_edges<<<(E + 255) / 256, 256, 0, stream>>>(dst, count, E);
    scan_block<<<nScan, 1024, 0, stream>>>(count, pre, bsum, N);
    scan_fix<<<(N + 255) / 256, 256, 0, stream>>>(pre, bsum, count, base, cursor, N, nScan);
    scatter_edges<<<(E + 255) / 256, 256, 0, stream>>>(src, dst, cursor, csr_src, E);

    // ---- adaLN: mod = silu(t) @ ada_w + ada_b  (bf16 out) ----
    gemm_mfma<4, 0, 1><<<dim3(6, rb128), 256, 0, stream>>>(
        Tbuf, ada_t, ada_b, modb, nullptr, nullptr, nullptr, N, 128, 768);

    // ---- xm = modulate(ln(x), shift_msa, scale_msa) ----
    ln_mod_kernel<<<(N + 3) / 4, 256, 0, stream>>>(x, modb, 0, 128, Bbuf, N);

    // ---- fused q|kv|skip GEMM -> packed QKV (q,kv fp8) ----
    gemm_mfma<4, 4, 1><<<dim3(13, rb128), 256, 0, stream>>>(
        Bbuf, Wsa_t, bsa, QKV, nullptr, nullptr, nullptr, N, 128, 1664);

    // ---- graph attention + residual + fused norm3 -> x1 (f32), qn (bf16) ----
    sa_node_kernel<<<N, 64, 0, stream>>>(QKV, base, csr_src, x, modb,
                                         n3_g, n3_b, Gbuf, Qn);

    // ---- cross attention (folded): qw fp8 ----
    gemm_mfma<4, 6, 0><<<dim3(4, rb128), 256, 0, stream>>>(
        Qn, Mcat_t, biasM, Cbuf, nullptr, nullptr, nullptr, N, 128, 512);
    cross_mid_kernel<<<N, 128, 0, stream>>>(te, Cbuf, Dbuf);
    // x2 = x1 + u@Pcat + co; fused MLP LN+modulate -> Bbuf (xm2)
    gemm_mfma<2, 5, 0><<<dim3(1, rb64), 256, 0, stream>>>(
        Dbuf, Pcat_t, co, Gbuf, Gbuf, modb, Bbuf, N, 512, 128);

    // ---- MLP ----
    gemm_mfma<4, 1, 1><<<dim3(4, rb128), 256, 0, stream>>>(
        Bbuf, fc1_t, fc1_b, Ebuf, nullptr, nullptr, nullptr, N, 128, 512);
    gemm_mfma<2, 3, 0><<<dim3(1, rb64), 256, 0, stream>>>(
        Ebuf, fc2_t, fc2_b, out, Gbuf, modb + 640, nullptr, N, 512, 128);
}